// Round 4
// baseline (864.165 us; speedup 1.0000x reference)
//
#include <hip/hip_runtime.h>

#define NDRUG 2528   // 32*79
#define NPROT 6144   // 32*192
#define NTOT  8672
#define EDRUG 5120
#define EPROT 12800
#define ETOT  17920   // EDRUG+EPROT
#define SEIN  15168
#define SEHID 2000

// ---------------- generic 16-row x 128-col GEMM with bias+relu (MLP layers) ----
__global__ void gemm_rt(const float* __restrict__ A, const float* __restrict__ B,
                        const float* __restrict__ bias, float* __restrict__ C, int K) {
    __shared__ float al[16 * 128];
    const int r0 = blockIdx.x * 16;
    const int j  = threadIdx.x;   // 128 threads
    for (int idx = j; idx < 16 * K; idx += 128) al[idx] = A[r0 * K + idx];
    __syncthreads();
    float acc[16];
#pragma unroll
    for (int r = 0; r < 16; r++) acc[r] = 0.f;
    for (int k = 0; k < K; k++) {
        float bv = B[k * 128 + j];
#pragma unroll
        for (int r = 0; r < 16; r++) acc[r] += al[r * K + k] * bv;
    }
    float bb = bias[j];
#pragma unroll
    for (int r = 0; r < 16; r++) C[(r0 + r) * 128 + j] = fmaxf(acc[r] + bb, 0.f);
}

// ---------------- GAT: h = x@W (K=N=128) + per-node as/ad + init agg/denom ------
__global__ void gat_h(const float* __restrict__ X, const float* __restrict__ W,
                      const float* __restrict__ avs, const float* __restrict__ avd,
                      float* __restrict__ H, float* __restrict__ asn, float* __restrict__ adn,
                      float* __restrict__ denom, float* __restrict__ agg) {
    __shared__ float al[16 * 128];
    __shared__ float hl[16][129];
    const int r0 = blockIdx.x * 16;
    const int j  = threadIdx.x;   // 128 threads
    for (int idx = j; idx < 16 * 128; idx += 128) al[idx] = X[r0 * 128 + idx];
    __syncthreads();
    float acc[16];
#pragma unroll
    for (int r = 0; r < 16; r++) acc[r] = 0.f;
    for (int k = 0; k < 128; k++) {
        float bv = W[k * 128 + j];
#pragma unroll
        for (int r = 0; r < 16; r++) acc[r] += al[r * 128 + k] * bv;
    }
#pragma unroll
    for (int r = 0; r < 16; r++) {
        H[(r0 + r) * 128 + j] = acc[r];
        hl[r][j] = acc[r];
        agg[(r0 + r) * 128 + j] = 0.f;
    }
    __syncthreads();
    int r = j >> 3, l8 = j & 7;
    float ps = 0.f, pd = 0.f;
    for (int jj = l8; jj < 128; jj += 8) {
        float v = hl[r][jj];
        ps += v * avs[jj];
        pd += v * avd[jj];
    }
    ps += __shfl_down(ps, 4); ps += __shfl_down(ps, 2); ps += __shfl_down(ps, 1);
    pd += __shfl_down(pd, 4); pd += __shfl_down(pd, 2); pd += __shfl_down(pd, 1);
    if (l8 == 0) { asn[r0 + r] = ps; adn[r0 + r] = pd; denom[r0 + r] = 0.f; }
}

// ---------------- GAT edge pass: w=exp(leaky(as[s]+ad[d])); accumulate ----------
__global__ void gat_edge(const int* __restrict__ de, const int* __restrict__ pe,
                         const float* __restrict__ asn, const float* __restrict__ adn,
                         const float* __restrict__ H, float* __restrict__ agg,
                         float* __restrict__ denom) {
    int gid = blockIdx.x * 256 + threadIdx.x;   // ETOT*128 items exactly
    int e = gid >> 7, f = gid & 127;
    int s, d;
    if (e < EDRUG) { s = de[e]; d = de[EDRUG + e]; }
    else { int ep = e - EDRUG; s = pe[ep] + NDRUG; d = pe[EPROT + ep] + NDRUG; }
    float ev = asn[s] + adn[d];
    ev = (ev > 0.f) ? ev : 0.2f * ev;
    float w = __expf(ev);
    atomicAdd(&agg[d * 128 + f], w * H[s * 128 + f]);
    if (f == 0) atomicAdd(&denom[d], w);
}

// ---------------- GAT finalize: add self loop, normalize, bias, relu, xsum ------
__global__ void gat_final(const float* __restrict__ agg, const float* __restrict__ denom,
                          const float* __restrict__ asn, const float* __restrict__ adn,
                          const float* __restrict__ H, const float* __restrict__ bd,
                          const float* __restrict__ bp, float* __restrict__ Xo,
                          float* __restrict__ xsum, int first) {
    int gid = blockIdx.x * 256 + threadIdx.x;   // NTOT*128 items exactly
    int i = gid >> 7, f = gid & 127;
    float ev = asn[i] + adn[i];
    ev = (ev > 0.f) ? ev : 0.2f * ev;
    float wself = __expf(ev);
    float bias = (i < NDRUG) ? bd[f] : bp[f];
    float val = (agg[gid] + wself * H[gid]) / (denom[i] + wself) + bias;
    val = fmaxf(val, 0.f);
    Xo[gid] = val;
    xsum[gid] = first ? val : (xsum[gid] + val);
}

// ---------------- per-node feature sum of xsum ---------------------------------
__global__ void rowsum(const float* __restrict__ xs, float* __restrict__ sl) {
    int n = blockIdx.x, t = threadIdx.x;  // 64 threads
    float v = xs[n * 128 + t] + xs[n * 128 + t + 64];
    for (int off = 32; off > 0; off >>= 1) v += __shfl_down(v, off);
    if (t == 0) sl[n] = v;
}

// ---------------- WR1[i,k] = sum_j se1w[(i*192+j)*2000+k] (stream 121MB) --------
__global__ void wr1k(const float* __restrict__ W, float* __restrict__ WR1) {
    int k = blockIdx.y * 256 + threadIdx.x;
    int i = blockIdx.x;                       // 0..78
    if (k >= SEHID) return;
    const float* p = W + (size_t)(i * 192) * SEHID + k;
    float a0 = 0.f, a1 = 0.f, a2 = 0.f, a3 = 0.f;
    for (int j = 0; j < 192; j += 4) {
        a0 += p[0];
        a1 += p[(size_t)SEHID];
        a2 += p[2 * (size_t)SEHID];
        a3 += p[3 * (size_t)SEHID];
        p += 4 * (size_t)SEHID;
    }
    WR1[i * SEHID + k] = (a0 + a1) + (a2 + a3);
}

// ---------------- WC1[j,k] = sum_i se1w[(i*192+j)*2000+k] (L3-warm 2nd pass) ----
__global__ void wc1k(const float* __restrict__ W, float* __restrict__ WC1) {
    int k = blockIdx.y * 256 + threadIdx.x;
    int j = blockIdx.x;                       // 0..191
    if (k >= SEHID) return;
    const float* p = W + (size_t)j * SEHID + k;
    const size_t st = (size_t)192 * SEHID;
    float a0 = 0.f, a1 = 0.f, a2 = 0.f, a3 = 0.f;
    int i = 0;
    for (; i < 76; i += 4) {
        a0 += p[0]; a1 += p[st]; a2 += p[2 * st]; a3 += p[3 * st];
        p += 4 * st;
    }
    a0 += p[0]; a1 += p[st]; a2 += p[2 * st];   // 76,77,78
    WC1[j * SEHID + k] = (a0 + a1) + (a2 + a3);
}

// ---------------- cmid = relu((slr@WR1 + slp@WC1)/256 + b); also transposed -----
__global__ void se1_small(const float* __restrict__ sl, const float* __restrict__ WR1,
                          const float* __restrict__ WC1, const float* __restrict__ bias,
                          float* __restrict__ cmid, float* __restrict__ cmidT) {
    int k = blockIdx.x * 256 + threadIdx.x;   // grid.x = 8
    int b = blockIdx.y;                       // 32
    if (k >= SEHID) return;
    float acc = 0.f;
    for (int i = 0; i < 79; i++)  acc += sl[b * 79 + i] * WR1[i * SEHID + k];
    for (int j = 0; j < 192; j++) acc += sl[NDRUG + b * 192 + j] * WC1[j * SEHID + k];
    float v = fmaxf(acc * (1.f / 256.f) + bias[k], 0.f);
    cmid[b * SEHID + k] = v;
    cmidT[k * 32 + b]   = v;
}

// ---------------- SE2: (32 x 2000) @ (2000 x 15168), LDS-staged A ---------------
// grid (30, 8); block 256; thread = 2 consecutive ij; k-range 250 per split.
// cmidT slice (250x32 = 32KB) staged in LDS once -> inner loop has ONE vmem op.
__global__ __launch_bounds__(256) void se2_partial(const float* __restrict__ cmidT,
                                                   const float* __restrict__ W,
                                                   float* __restrict__ part) {
    __shared__ float cs[250 * 32];            // 32 KB
    const int ij = blockIdx.x * 512 + threadIdx.x * 2;
    const int ks = blockIdx.y * 250;
    const float4* csrc = (const float4*)(cmidT + ks * 32);   // 16B-aligned
    for (int idx = threadIdx.x; idx < 2000; idx += 256)
        ((float4*)cs)[idx] = csrc[idx];
    __syncthreads();
    const bool in = ij < SEIN;
    float2 acc[32];
#pragma unroll
    for (int b = 0; b < 32; b++) { acc[b].x = 0.f; acc[b].y = 0.f; }
    const float* wp = W + (size_t)ks * SEIN + ij;
    for (int kk = 0; kk < 250; kk++) {
        float2 w;
        if (in) w = *(const float2*)wp; else { w.x = 0.f; w.y = 0.f; }
        wp += SEIN;
        const float* cp = cs + kk * 32;
#pragma unroll
        for (int b4 = 0; b4 < 32; b4 += 4) {
            float4 a = *(const float4*)(cp + b4);   // uniform addr -> LDS broadcast
            acc[b4 + 0].x += a.x * w.x; acc[b4 + 0].y += a.x * w.y;
            acc[b4 + 1].x += a.y * w.x; acc[b4 + 1].y += a.y * w.y;
            acc[b4 + 2].x += a.z * w.x; acc[b4 + 2].y += a.z * w.y;
            acc[b4 + 3].x += a.w * w.x; acc[b4 + 3].y += a.w * w.y;
        }
    }
    if (in) {
        float* pp = part + (size_t)(blockIdx.y * 32) * 15360 + ij;
#pragma unroll
        for (int b = 0; b < 32; b++) { *(float2*)pp = acc[b]; pp += 15360; }
    }
}

__global__ void se2_red(const float* __restrict__ part, const float* __restrict__ bias,
                        const float* __restrict__ inter, float* __restrict__ wgt) {
    int gid = blockIdx.x * 256 + threadIdx.x;   // 32*15168 exactly, grid 1896
    int b = gid / SEIN, ij = gid % SEIN;
    float s = 0.f;
#pragma unroll
    for (int sp = 0; sp < 8; sp++) s += part[(size_t)(sp * 32 + b) * 15360 + ij];
    s += bias[ij];
    float sig = 1.f / (1.f + __expf(-s));
    wgt[gid] = sig / inter[gid];
}

// ---------------- row/col sums of wgt over the (79,192) grid (barrier-free) -----
__global__ void wsum(const float* __restrict__ wgt, float* __restrict__ wr,
                     float* __restrict__ wc) {
    int b = blockIdx.x, t = threadIdx.x;   // 256 threads
    if (t < 192) {                          // column sums: coalesced strided reads
        float s = 0.f;
        for (int i = 0; i < 79; i++) s += wgt[b * SEIN + i * 192 + t];
        wc[b * 192 + t] = s;
    }
    int wv = t >> 6, ln = t & 63;           // row sums: one wave per row
    for (int i = wv; i < 79; i += 4) {
        float v = 0.f;
        for (int j = ln; j < 192; j += 64) v += wgt[b * SEIN + i * 192 + j];
        v += __shfl_down(v, 32); v += __shfl_down(v, 16); v += __shfl_down(v, 8);
        v += __shfl_down(v, 4);  v += __shfl_down(v, 2);  v += __shfl_down(v, 1);
        if (ln == 0) wr[b * 79 + i] = v;
    }
}

// ---------------- xx[b,0:128] = x_l^T wr /15168 ; xx[b,128:256] = x_p^T wc ------
__global__ void xxk(const float* __restrict__ xs, const float* __restrict__ wr,
                    const float* __restrict__ wc, float* __restrict__ xx) {
    int b = blockIdx.x, t = threadIdx.x;   // 256 threads
    float acc = 0.f;
    if (t < 128) {
        for (int i = 0; i < 79; i++) acc += xs[(b * 79 + i) * 128 + t] * wr[b * 79 + i];
    } else {
        int f = t - 128;
        for (int j = 0; j < 192; j++) acc += xs[(NDRUG + b * 192 + j) * 128 + f] * wc[b * 192 + j];
    }
    xx[b * 256 + t] = acc * (1.f / 15168.f);
}

// ---------------- head GEMM: one thread per (b,col); acc=1 -> deep ILP ----------
__global__ void mlp_gemm(const float* __restrict__ A, const float* __restrict__ W,
                         const float* __restrict__ bias, float* __restrict__ Raw,
                         float* __restrict__ C, int K, int N, int relu) {
    const int bb = threadIdx.x >> 5, cl = threadIdx.x & 31;
    const int b = blockIdx.y * 8 + bb;
    const int col = blockIdx.x * 32 + cl;
    __shared__ float As[8][64];
    float acc = 0.f;
    for (int k0 = 0; k0 < K; k0 += 64) {
        __syncthreads();
        int idx = threadIdx.x;
        As[idx >> 6][idx & 63] = A[(blockIdx.y * 8 + (idx >> 6)) * K + k0 + (idx & 63)];
        idx += 256;
        As[idx >> 6][idx & 63] = A[(blockIdx.y * 8 + (idx >> 6)) * K + k0 + (idx & 63)];
        __syncthreads();
#pragma unroll 8
        for (int kk = 0; kk < 64; kk++)
            acc += As[bb][kk] * W[(k0 + kk) * N + col];
    }
    float v = acc + bias[col];
    if (Raw) Raw[b * N + col] = v;
    C[b * N + col] = relu ? fmaxf(v, 0.f) : v;
}

// ---------------- final 64->1 projection ---------------------------------------
__global__ void outk(const float* __restrict__ r4, const float* __restrict__ OW,
                     const float* __restrict__ OB, float* __restrict__ outp) {
    int t = threadIdx.x;            // 256 threads = 32 b x 8 lanes
    int b = t >> 3, l = t & 7;
    float v = 0.f;
    for (int j = l; j < 64; j += 8) v += r4[b * 64 + j] * OW[j];
    v += __shfl_down(v, 4); v += __shfl_down(v, 2); v += __shfl_down(v, 1);
    if (l == 0) outp[b] = v + OB[0];
}

extern "C" void kernel_launch(void* const* d_in, const int* in_sizes, int n_in,
                              void* d_out, int out_size, void* d_ws, size_t ws_size,
                              hipStream_t stream) {
    const float* x1    = (const float*)d_in[0];
    const float* x2    = (const float*)d_in[1];
    const float* inter = (const float*)d_in[2];
    const int*   de    = (const int*)d_in[3];
    const int*   pe    = (const int*)d_in[4];
    const float* w1    = (const float*)d_in[5];
    const float* b1    = (const float*)d_in[6];
    const float* w2    = (const float*)d_in[7];
    const float* b2    = (const float*)d_in[8];
    const float* gw    = (const float*)d_in[9];
    const float* gas   = (const float*)d_in[10];
    const float* gad   = (const float*)d_in[11];
    const float* gb    = (const float*)d_in[12];
    const float* se1w  = (const float*)d_in[13];
    const float* se1b  = (const float*)d_in[14];
    const float* se2w  = (const float*)d_in[15];
    const float* se2b  = (const float*)d_in[16];
    const float* fc1w  = (const float*)d_in[17];
    const float* fc1b  = (const float*)d_in[18];
    const float* fc2w  = (const float*)d_in[19];
    const float* fc2b  = (const float*)d_in[20];
    const float* fc3w  = (const float*)d_in[21];
    const float* fc3b  = (const float*)d_in[22];
    const float* fc4w  = (const float*)d_in[23];
    const float* fc4b  = (const float*)d_in[24];
    const float* outw  = (const float*)d_in[25];
    const float* outb  = (const float*)d_in[26];
    float* out = (float*)d_out;
    float* ws  = (float*)d_ws;

    const size_t NF = (size_t)NTOT * 128;   // 1,110,016
    // GAT region (xsum deliberately LAST so se2 partials can alias xA..agg)
    float* xA    = ws;
    float* xB    = ws + NF;
    float* hbuf  = ws + 2 * NF;
    float* agg   = ws + 3 * NF;
    float* xsum  = ws + 4 * NF;
    float* part  = ws;                      // alias: 8*32*15360 = 3.93M < 4*NF
    float* sm    = ws + 5 * NF;
    float* asn   = sm;                     sm += NTOT;
    float* adn   = sm;                     sm += NTOT;
    float* denom = sm;                     sm += NTOT;
    float* sl    = sm;                     sm += NTOT;
    float* WR1   = sm;                     sm += 79 * SEHID;    // 158000
    float* WC1   = sm;                     sm += 192 * SEHID;   // 384000
    float* cmid  = sm;                     sm += 32 * SEHID;
    float* cmidT = sm;                     sm += 32 * SEHID;
    float* wgt   = sm;                     sm += 32 * SEIN;     // 485376
    float* wr    = sm;                     sm += 32 * 79;
    float* wc    = sm;                     sm += 32 * 192;
    float* xx    = sm;                     sm += 32 * 256;
    float* r1    = sm;                     sm += 32 * 512;
    float* r2    = sm;                     sm += 32 * 256;
    float* r3    = sm;                     sm += 32 * 128;
    float* r4    = sm;                     sm += 32 * 64;

    // SE1 weight reductions (independent of GAT results — issue early;
    // wc1k immediately after wr1k so the 121MB se1w is L3-resident)
    wr1k<<<dim3(79, 8), 256, 0, stream>>>(se1w, WR1);
    wc1k<<<dim3(192, 8), 256, 0, stream>>>(se1w, WC1);

    // shared node-embedding MLP (x1 and x2 through w1/w2); stage 1 in xB
    gemm_rt<<<158, 128, 0, stream>>>(x1, w1, b1, xB, 52);
    gemm_rt<<<384, 128, 0, stream>>>(x2, w1, b1, xB + (size_t)NDRUG * 128, 52);
    gemm_rt<<<158, 128, 0, stream>>>(xB, w2, b2, xA, 128);
    gemm_rt<<<384, 128, 0, stream>>>(xB + (size_t)NDRUG * 128, w2, b2, xA + (size_t)NDRUG * 128, 128);

    float* xin = xA;
    float* xout = xB;
    for (int l = 0; l < 3; l++) {
        gat_h<<<158, 128, 0, stream>>>(xin, gw + l * 16384, gas + l * 128, gad + l * 128,
                                       hbuf, asn, adn, denom, agg);
        gat_h<<<384, 128, 0, stream>>>(xin + (size_t)NDRUG * 128, gw + (l + 3) * 16384,
                                       gas + (l + 3) * 128, gad + (l + 3) * 128,
                                       hbuf + (size_t)NDRUG * 128, asn + NDRUG, adn + NDRUG,
                                       denom + NDRUG, agg + (size_t)NDRUG * 128);
        gat_edge<<<8960, 256, 0, stream>>>(de, pe, asn, adn, hbuf, agg, denom);
        gat_final<<<4336, 256, 0, stream>>>(agg, denom, asn, adn, hbuf,
                                            gb + l * 128, gb + (l + 3) * 128,
                                            xout, xsum, l == 0 ? 1 : 0);
        float* tmp = xin; xin = xout; xout = tmp;
    }

    rowsum<<<NTOT, 64, 0, stream>>>(xsum, sl);
    se1_small<<<dim3(8, 32), 256, 0, stream>>>(sl, WR1, WC1, se1b, cmid, cmidT);
    se2_partial<<<dim3(30, 8), 256, 0, stream>>>(cmidT, se2w, part);
    se2_red<<<1896, 256, 0, stream>>>(part, se2b, inter, wgt);
    wsum<<<32, 256, 0, stream>>>(wgt, wr, wc);
    xxk<<<32, 256, 0, stream>>>(xsum, wr, wc, xx);

    mlp_gemm<<<dim3(16, 4), 256, 0, stream>>>(xx, fc1w, fc1b, out + 32, r1, 256, 512, 1);
    mlp_gemm<<<dim3(8, 4), 256, 0, stream>>>(r1, fc2w, fc2b, nullptr, r2, 512, 256, 1);
    mlp_gemm<<<dim3(4, 4), 256, 0, stream>>>(r2, fc3w, fc3b, nullptr, r3, 256, 128, 1);
    mlp_gemm<<<dim3(2, 4), 256, 0, stream>>>(r3, fc4w, fc4b, nullptr, r4, 128, 64, 1);
    outk<<<1, 256, 0, stream>>>(r4, outw, outb, out);
}

// Round 5
// 793.024 us; speedup vs baseline: 1.0897x; 1.0897x over previous
//
#include <hip/hip_runtime.h>

#define NDRUG 2528   // 32*79
#define NPROT 6144   // 32*192
#define NTOT  8672
#define EDRUG 5120
#define EPROT 12800
#define ETOT  17920   // EDRUG+EPROT
#define SEIN  15168
#define SEHID 2000

// ---------------- generic 16-row x 128-col GEMM with bias+relu (MLP layers) ----
__global__ void gemm_rt(const float* __restrict__ A, const float* __restrict__ B,
                        const float* __restrict__ bias, float* __restrict__ C, int K) {
    __shared__ float al[16 * 128];
    const int r0 = blockIdx.x * 16;
    const int j  = threadIdx.x;   // 128 threads
    for (int idx = j; idx < 16 * K; idx += 128) al[idx] = A[r0 * K + idx];
    __syncthreads();
    float acc[16];
#pragma unroll
    for (int r = 0; r < 16; r++) acc[r] = 0.f;
    for (int k = 0; k < K; k++) {
        float bv = B[k * 128 + j];
#pragma unroll
        for (int r = 0; r < 16; r++) acc[r] += al[r * K + k] * bv;
    }
    float bb = bias[j];
#pragma unroll
    for (int r = 0; r < 16; r++) C[(r0 + r) * 128 + j] = fmaxf(acc[r] + bb, 0.f);
}

// ---------------- GAT: h = x@W (K=N=128) + per-node as/ad + init agg/denom ------
__global__ void gat_h(const float* __restrict__ X, const float* __restrict__ W,
                      const float* __restrict__ avs, const float* __restrict__ avd,
                      float* __restrict__ H, float* __restrict__ asn, float* __restrict__ adn,
                      float* __restrict__ denom, float* __restrict__ agg) {
    __shared__ float al[16 * 128];
    __shared__ float hl[16][129];
    const int r0 = blockIdx.x * 16;
    const int j  = threadIdx.x;   // 128 threads
    for (int idx = j; idx < 16 * 128; idx += 128) al[idx] = X[r0 * 128 + idx];
    __syncthreads();
    float acc[16];
#pragma unroll
    for (int r = 0; r < 16; r++) acc[r] = 0.f;
    for (int k = 0; k < 128; k++) {
        float bv = W[k * 128 + j];
#pragma unroll
        for (int r = 0; r < 16; r++) acc[r] += al[r * 128 + k] * bv;
    }
#pragma unroll
    for (int r = 0; r < 16; r++) {
        H[(r0 + r) * 128 + j] = acc[r];
        hl[r][j] = acc[r];
        agg[(r0 + r) * 128 + j] = 0.f;
    }
    __syncthreads();
    int r = j >> 3, l8 = j & 7;
    float ps = 0.f, pd = 0.f;
    for (int jj = l8; jj < 128; jj += 8) {
        float v = hl[r][jj];
        ps += v * avs[jj];
        pd += v * avd[jj];
    }
    ps += __shfl_down(ps, 4); ps += __shfl_down(ps, 2); ps += __shfl_down(ps, 1);
    pd += __shfl_down(pd, 4); pd += __shfl_down(pd, 2); pd += __shfl_down(pd, 1);
    if (l8 == 0) { asn[r0 + r] = ps; adn[r0 + r] = pd; denom[r0 + r] = 0.f; }
}

// ---------------- GAT edge pass: w=exp(leaky(as[s]+ad[d])); accumulate ----------
__global__ void gat_edge(const int* __restrict__ de, const int* __restrict__ pe,
                         const float* __restrict__ asn, const float* __restrict__ adn,
                         const float* __restrict__ H, float* __restrict__ agg,
                         float* __restrict__ denom) {
    int gid = blockIdx.x * 256 + threadIdx.x;   // ETOT*128 items exactly
    int e = gid >> 7, f = gid & 127;
    int s, d;
    if (e < EDRUG) { s = de[e]; d = de[EDRUG + e]; }
    else { int ep = e - EDRUG; s = pe[ep] + NDRUG; d = pe[EPROT + ep] + NDRUG; }
    float ev = asn[s] + adn[d];
    ev = (ev > 0.f) ? ev : 0.2f * ev;
    float w = __expf(ev);
    atomicAdd(&agg[d * 128 + f], w * H[s * 128 + f]);
    if (f == 0) atomicAdd(&denom[d], w);
}

// ---------------- GAT finalize: add self loop, normalize, bias, relu, xsum ------
__global__ void gat_final(const float* __restrict__ agg, const float* __restrict__ denom,
                          const float* __restrict__ asn, const float* __restrict__ adn,
                          const float* __restrict__ H, const float* __restrict__ bd,
                          const float* __restrict__ bp, float* __restrict__ Xo,
                          float* __restrict__ xsum, int first) {
    int gid = blockIdx.x * 256 + threadIdx.x;   // NTOT*128 items exactly
    int i = gid >> 7, f = gid & 127;
    float ev = asn[i] + adn[i];
    ev = (ev > 0.f) ? ev : 0.2f * ev;
    float wself = __expf(ev);
    float bias = (i < NDRUG) ? bd[f] : bp[f];
    float val = (agg[gid] + wself * H[gid]) / (denom[i] + wself) + bias;
    val = fmaxf(val, 0.f);
    Xo[gid] = val;
    xsum[gid] = first ? val : (xsum[gid] + val);
}

// ---------------- per-node feature sum of xsum ---------------------------------
__global__ void rowsum(const float* __restrict__ xs, float* __restrict__ sl) {
    int n = blockIdx.x, t = threadIdx.x;  // 64 threads
    float v = xs[n * 128 + t] + xs[n * 128 + t + 64];
    for (int off = 32; off > 0; off >>= 1) v += __shfl_down(v, off);
    if (t == 0) sl[n] = v;
}

// ---------------- WR1[i,k] = sum_j se1w[(i*192+j)*2000+k] (stream 121MB) --------
__global__ void wr1k(const float* __restrict__ W, float* __restrict__ WR1) {
    int k = blockIdx.y * 256 + threadIdx.x;
    int i = blockIdx.x;                       // 0..78
    if (k >= SEHID) return;
    const float* p = W + (size_t)(i * 192) * SEHID + k;
    float a0 = 0.f, a1 = 0.f, a2 = 0.f, a3 = 0.f;
    for (int j = 0; j < 192; j += 4) {
        a0 += p[0];
        a1 += p[(size_t)SEHID];
        a2 += p[2 * (size_t)SEHID];
        a3 += p[3 * (size_t)SEHID];
        p += 4 * (size_t)SEHID;
    }
    WR1[i * SEHID + k] = (a0 + a1) + (a2 + a3);
}

// ---------------- WC1[j,k] = sum_i se1w[(i*192+j)*2000+k] (L3-warm 2nd pass) ----
__global__ void wc1k(const float* __restrict__ W, float* __restrict__ WC1) {
    int k = blockIdx.y * 256 + threadIdx.x;
    int j = blockIdx.x;                       // 0..191
    if (k >= SEHID) return;
    const float* p = W + (size_t)j * SEHID + k;
    const size_t st = (size_t)192 * SEHID;
    float a0 = 0.f, a1 = 0.f, a2 = 0.f, a3 = 0.f;
    int i = 0;
    for (; i < 76; i += 4) {
        a0 += p[0]; a1 += p[st]; a2 += p[2 * st]; a3 += p[3 * st];
        p += 4 * st;
    }
    a0 += p[0]; a1 += p[st]; a2 += p[2 * st];   // 76,77,78
    WC1[j * SEHID + k] = (a0 + a1) + (a2 + a3);
}

// ---------------- cmid = relu((slr@WR1 + slp@WC1)/256 + b); also transposed -----
__global__ void se1_small(const float* __restrict__ sl, const float* __restrict__ WR1,
                          const float* __restrict__ WC1, const float* __restrict__ bias,
                          float* __restrict__ cmid, float* __restrict__ cmidT) {
    int k = blockIdx.x * 256 + threadIdx.x;   // grid.x = 8
    int b = blockIdx.y;                       // 32
    if (k >= SEHID) return;
    float acc = 0.f;
    for (int i = 0; i < 79; i++)  acc += sl[b * 79 + i] * WR1[i * SEHID + k];
    for (int j = 0; j < 192; j++) acc += sl[NDRUG + b * 192 + j] * WC1[j * SEHID + k];
    float v = fmaxf(acc * (1.f / 256.f) + bias[k], 0.f);
    cmid[b * SEHID + k] = v;
    cmidT[k * 32 + b]   = v;
}

// ---------------- sgate[b,ij] = se2b[ij]  (accumulation target for se2) ---------
__global__ void sgate_init(const float* __restrict__ bias, float* __restrict__ sgate) {
    int gid = blockIdx.x * 256 + threadIdx.x;   // 32*15168 exactly, grid 1896
    sgate[gid] = bias[gid % SEIN];
}

// ---------------- SE2: (32 x 2000) @ (2000 x 15168), atomic split-K -------------
// grid (30, 16); block 256; thread = 2 consecutive ij; k-range 125 per split.
// cmidT slice (125x32 = 16KB) in LDS; kk unrolled x5 with loads batched first
// so ~5 W-loads stay in flight per wave; 480 blocks -> ~8 waves/CU.
__global__ __launch_bounds__(256) void se2_partial(const float* __restrict__ cmidT,
                                                   const float* __restrict__ W,
                                                   float* __restrict__ sgate) {
    __shared__ float cs[125 * 32];            // 16 KB
    const int ij = blockIdx.x * 512 + threadIdx.x * 2;
    const int ks = blockIdx.y * 125;
    const float4* csrc = (const float4*)(cmidT + ks * 32);   // 16B-aligned
    for (int idx = threadIdx.x; idx < 1000; idx += 256)
        ((float4*)cs)[idx] = csrc[idx];
    __syncthreads();
    const bool in = ij < SEIN;
    float2 acc[32];
#pragma unroll
    for (int b = 0; b < 32; b++) { acc[b].x = 0.f; acc[b].y = 0.f; }
    const float* wp = W + (size_t)ks * SEIN + ij;
    for (int kk = 0; kk < 125; kk += 5) {
        float2 w[5];
#pragma unroll
        for (int t = 0; t < 5; t++) {
            if (in) w[t] = *(const float2*)(wp + (size_t)t * SEIN);
            else { w[t].x = 0.f; w[t].y = 0.f; }
        }
        wp += 5 * (size_t)SEIN;
#pragma unroll
        for (int t = 0; t < 5; t++) {
            const float* cp = cs + (kk + t) * 32;
#pragma unroll
            for (int b4 = 0; b4 < 32; b4 += 4) {
                float4 a = *(const float4*)(cp + b4);   // uniform addr -> LDS broadcast
                acc[b4 + 0].x += a.x * w[t].x; acc[b4 + 0].y += a.x * w[t].y;
                acc[b4 + 1].x += a.y * w[t].x; acc[b4 + 1].y += a.y * w[t].y;
                acc[b4 + 2].x += a.z * w[t].x; acc[b4 + 2].y += a.z * w[t].y;
                acc[b4 + 3].x += a.w * w[t].x; acc[b4 + 3].y += a.w * w[t].y;
            }
        }
    }
    if (in) {
        float* pp = sgate + ij;
#pragma unroll
        for (int b = 0; b < 32; b++) {
            atomicAdd(pp,     acc[b].x);
            atomicAdd(pp + 1, acc[b].y);
            pp += SEIN;
        }
    }
}

// ---------------- wgt = sigmoid(sgate) / inter ----------------------------------
__global__ void se2_fin(const float* __restrict__ sgate, const float* __restrict__ inter,
                        float* __restrict__ wgt) {
    int gid = blockIdx.x * 256 + threadIdx.x;   // 32*15168 exactly, grid 1896
    float s = sgate[gid];
    float sig = 1.f / (1.f + __expf(-s));
    wgt[gid] = sig / inter[gid];
}

// ---------------- row/col sums of wgt over the (79,192) grid (barrier-free) -----
__global__ void wsum(const float* __restrict__ wgt, float* __restrict__ wr,
                     float* __restrict__ wc) {
    int b = blockIdx.x, t = threadIdx.x;   // 256 threads
    if (t < 192) {                          // column sums: coalesced strided reads
        float s = 0.f;
        for (int i = 0; i < 79; i++) s += wgt[b * SEIN + i * 192 + t];
        wc[b * 192 + t] = s;
    }
    int wv = t >> 6, ln = t & 63;           // row sums: one wave per row
    for (int i = wv; i < 79; i += 4) {
        float v = 0.f;
        for (int j = ln; j < 192; j += 64) v += wgt[b * SEIN + i * 192 + j];
        v += __shfl_down(v, 32); v += __shfl_down(v, 16); v += __shfl_down(v, 8);
        v += __shfl_down(v, 4);  v += __shfl_down(v, 2);  v += __shfl_down(v, 1);
        if (ln == 0) wr[b * 79 + i] = v;
    }
}

// ---------------- xx[b,0:128] = x_l^T wr /15168 ; xx[b,128:256] = x_p^T wc ------
__global__ void xxk(const float* __restrict__ xs, const float* __restrict__ wr,
                    const float* __restrict__ wc, float* __restrict__ xx) {
    int b = blockIdx.x, t = threadIdx.x;   // 256 threads
    float acc = 0.f;
    if (t < 128) {
        for (int i = 0; i < 79; i++) acc += xs[(b * 79 + i) * 128 + t] * wr[b * 79 + i];
    } else {
        int f = t - 128;
        for (int j = 0; j < 192; j++) acc += xs[(NDRUG + b * 192 + j) * 128 + f] * wc[b * 192 + j];
    }
    xx[b * 256 + t] = acc * (1.f / 15168.f);
}

// ---------------- head GEMM: one thread per (b,col); acc=1 -> deep ILP ----------
__global__ void mlp_gemm(const float* __restrict__ A, const float* __restrict__ W,
                         const float* __restrict__ bias, float* __restrict__ Raw,
                         float* __restrict__ C, int K, int N, int relu) {
    const int bb = threadIdx.x >> 5, cl = threadIdx.x & 31;
    const int b = blockIdx.y * 8 + bb;
    const int col = blockIdx.x * 32 + cl;
    __shared__ float As[8][64];
    float acc = 0.f;
    for (int k0 = 0; k0 < K; k0 += 64) {
        __syncthreads();
        int idx = threadIdx.x;
        As[idx >> 6][idx & 63] = A[(blockIdx.y * 8 + (idx >> 6)) * K + k0 + (idx & 63)];
        idx += 256;
        As[idx >> 6][idx & 63] = A[(blockIdx.y * 8 + (idx >> 6)) * K + k0 + (idx & 63)];
        __syncthreads();
#pragma unroll 8
        for (int kk = 0; kk < 64; kk++)
            acc += As[bb][kk] * W[(k0 + kk) * N + col];
    }
    float v = acc + bias[col];
    if (Raw) Raw[b * N + col] = v;
    C[b * N + col] = relu ? fmaxf(v, 0.f) : v;
}

// ---------------- final 64->1 projection ---------------------------------------
__global__ void outk(const float* __restrict__ r4, const float* __restrict__ OW,
                     const float* __restrict__ OB, float* __restrict__ outp) {
    int t = threadIdx.x;            // 256 threads = 32 b x 8 lanes
    int b = t >> 3, l = t & 7;
    float v = 0.f;
    for (int j = l; j < 64; j += 8) v += r4[b * 64 + j] * OW[j];
    v += __shfl_down(v, 4); v += __shfl_down(v, 2); v += __shfl_down(v, 1);
    if (l == 0) outp[b] = v + OB[0];
}

extern "C" void kernel_launch(void* const* d_in, const int* in_sizes, int n_in,
                              void* d_out, int out_size, void* d_ws, size_t ws_size,
                              hipStream_t stream) {
    const float* x1    = (const float*)d_in[0];
    const float* x2    = (const float*)d_in[1];
    const float* inter = (const float*)d_in[2];
    const int*   de    = (const int*)d_in[3];
    const int*   pe    = (const int*)d_in[4];
    const float* w1    = (const float*)d_in[5];
    const float* b1    = (const float*)d_in[6];
    const float* w2    = (const float*)d_in[7];
    const float* b2    = (const float*)d_in[8];
    const float* gw    = (const float*)d_in[9];
    const float* gas   = (const float*)d_in[10];
    const float* gad   = (const float*)d_in[11];
    const float* gb    = (const float*)d_in[12];
    const float* se1w  = (const float*)d_in[13];
    const float* se1b  = (const float*)d_in[14];
    const float* se2w  = (const float*)d_in[15];
    const float* se2b  = (const float*)d_in[16];
    const float* fc1w  = (const float*)d_in[17];
    const float* fc1b  = (const float*)d_in[18];
    const float* fc2w  = (const float*)d_in[19];
    const float* fc2b  = (const float*)d_in[20];
    const float* fc3w  = (const float*)d_in[21];
    const float* fc3b  = (const float*)d_in[22];
    const float* fc4w  = (const float*)d_in[23];
    const float* fc4b  = (const float*)d_in[24];
    const float* outw  = (const float*)d_in[25];
    const float* outb  = (const float*)d_in[26];
    float* out = (float*)d_out;
    float* ws  = (float*)d_ws;

    const size_t NF = (size_t)NTOT * 128;   // 1,110,016
    // GAT region (xsum deliberately LAST so sgate can alias xA..agg)
    float* xA    = ws;
    float* xB    = ws + NF;
    float* hbuf  = ws + 2 * NF;
    float* agg   = ws + 3 * NF;
    float* xsum  = ws + 4 * NF;
    float* sgate = ws;                      // alias: 32*15168 = 485K << 4*NF
    float* sm    = ws + 5 * NF;
    float* asn   = sm;                     sm += NTOT;
    float* adn   = sm;                     sm += NTOT;
    float* denom = sm;                     sm += NTOT;
    float* sl    = sm;                     sm += NTOT;
    float* WR1   = sm;                     sm += 79 * SEHID;    // 158000
    float* WC1   = sm;                     sm += 192 * SEHID;   // 384000
    float* cmid  = sm;                     sm += 32 * SEHID;
    float* cmidT = sm;                     sm += 32 * SEHID;
    float* wgt   = sm;                     sm += 32 * SEIN;     // 485376
    float* wr    = sm;                     sm += 32 * 79;
    float* wc    = sm;                     sm += 32 * 192;
    float* xx    = sm;                     sm += 32 * 256;
    float* r1    = sm;                     sm += 32 * 512;
    float* r2    = sm;                     sm += 32 * 256;
    float* r3    = sm;                     sm += 32 * 128;
    float* r4    = sm;                     sm += 32 * 64;

    // SE1 weight reductions (independent of GAT results — issue early;
    // wc1k immediately after wr1k so the 121MB se1w is L3-resident)
    wr1k<<<dim3(79, 8), 256, 0, stream>>>(se1w, WR1);
    wc1k<<<dim3(192, 8), 256, 0, stream>>>(se1w, WC1);

    // shared node-embedding MLP (x1 and x2 through w1/w2); stage 1 in xB
    gemm_rt<<<158, 128, 0, stream>>>(x1, w1, b1, xB, 52);
    gemm_rt<<<384, 128, 0, stream>>>(x2, w1, b1, xB + (size_t)NDRUG * 128, 52);
    gemm_rt<<<158, 128, 0, stream>>>(xB, w2, b2, xA, 128);
    gemm_rt<<<384, 128, 0, stream>>>(xB + (size_t)NDRUG * 128, w2, b2, xA + (size_t)NDRUG * 128, 128);

    float* xin = xA;
    float* xout = xB;
    for (int l = 0; l < 3; l++) {
        gat_h<<<158, 128, 0, stream>>>(xin, gw + l * 16384, gas + l * 128, gad + l * 128,
                                       hbuf, asn, adn, denom, agg);
        gat_h<<<384, 128, 0, stream>>>(xin + (size_t)NDRUG * 128, gw + (l + 3) * 16384,
                                       gas + (l + 3) * 128, gad + (l + 3) * 128,
                                       hbuf + (size_t)NDRUG * 128, asn + NDRUG, adn + NDRUG,
                                       denom + NDRUG, agg + (size_t)NDRUG * 128);
        gat_edge<<<8960, 256, 0, stream>>>(de, pe, asn, adn, hbuf, agg, denom);
        gat_final<<<4336, 256, 0, stream>>>(agg, denom, asn, adn, hbuf,
                                            gb + l * 128, gb + (l + 3) * 128,
                                            xout, xsum, l == 0 ? 1 : 0);
        float* tmp = xin; xin = xout; xout = tmp;
    }

    rowsum<<<NTOT, 64, 0, stream>>>(xsum, sl);
    se1_small<<<dim3(8, 32), 256, 0, stream>>>(sl, WR1, WC1, se1b, cmid, cmidT);
    sgate_init<<<1896, 256, 0, stream>>>(se2b, sgate);
    se2_partial<<<dim3(30, 16), 256, 0, stream>>>(cmidT, se2w, sgate);
    se2_fin<<<1896, 256, 0, stream>>>(sgate, inter, wgt);
    wsum<<<32, 256, 0, stream>>>(wgt, wr, wc);
    xxk<<<32, 256, 0, stream>>>(xsum, wr, wc, xx);

    mlp_gemm<<<dim3(16, 4), 256, 0, stream>>>(xx, fc1w, fc1b, out + 32, r1, 256, 512, 1);
    mlp_gemm<<<dim3(8, 4), 256, 0, stream>>>(r1, fc2w, fc2b, nullptr, r2, 512, 256, 1);
    mlp_gemm<<<dim3(4, 4), 256, 0, stream>>>(r2, fc3w, fc3b, nullptr, r3, 256, 128, 1);
    mlp_gemm<<<dim3(2, 4), 256, 0, stream>>>(r3, fc4w, fc4b, nullptr, r4, 128, 64, 1);
    outk<<<1, 256, 0, stream>>>(r4, outw, outb, out);
}

// Round 6
// 750.913 us; speedup vs baseline: 1.1508x; 1.0561x over previous
//
#include <hip/hip_runtime.h>

#define NDRUG 2528   // 32*79
#define NPROT 6144   // 32*192
#define NTOT  8672
#define EDRUG 5120
#define EPROT 12800
#define ETOT  17920   // EDRUG+EPROT
#define SEIN  15168
#define SEHID 2000

// ---------------- generic 16-row x 128-col GEMM with bias+relu (MLP layers) ----
__global__ void gemm_rt(const float* __restrict__ A, const float* __restrict__ B,
                        const float* __restrict__ bias, float* __restrict__ C, int K) {
    __shared__ float al[16 * 128];
    const int r0 = blockIdx.x * 16;
    const int j  = threadIdx.x;   // 128 threads
    for (int idx = j; idx < 16 * K; idx += 128) al[idx] = A[r0 * K + idx];
    __syncthreads();
    float acc[16];
#pragma unroll
    for (int r = 0; r < 16; r++) acc[r] = 0.f;
    for (int k = 0; k < K; k++) {
        float bv = B[k * 128 + j];
#pragma unroll
        for (int r = 0; r < 16; r++) acc[r] += al[r * K + k] * bv;
    }
    float bb = bias[j];
#pragma unroll
    for (int r = 0; r < 16; r++) C[(r0 + r) * 128 + j] = fmaxf(acc[r] + bb, 0.f);
}

// ---------------- CSR build (edges identical across all 3 GAT layers) -----------
__global__ void csr_zero(int* __restrict__ deg, int* __restrict__ fill) {
    int gid = blockIdx.x * 256 + threadIdx.x;
    if (gid < NTOT) { deg[gid] = 0; fill[gid] = 0; }
}

__global__ void csr_cnt(const int* __restrict__ de, const int* __restrict__ pe,
                        int* __restrict__ deg) {
    int e = blockIdx.x * 256 + threadIdx.x;
    if (e >= ETOT) return;
    int d;
    if (e < EDRUG) d = de[EDRUG + e];
    else d = pe[EPROT + (e - EDRUG)] + NDRUG;
    atomicAdd(&deg[d], 1);
}

__global__ void csr_scan(const int* __restrict__ deg, int* __restrict__ off) {
    __shared__ int tot[1024];
    const int t = threadIdx.x;        // 1024 threads
    int loc[9];
    int s = 0;
    int base = t * 9;                 // 1024*9 = 9216 >= NTOT
#pragma unroll
    for (int c = 0; c < 9; c++) {
        int idx = base + c;
        int v = (idx < NTOT) ? deg[idx] : 0;
        loc[c] = s; s += v;
    }
    tot[t] = s;
    __syncthreads();
    for (int d = 1; d < 1024; d <<= 1) {
        int v = (t >= d) ? tot[t - d] : 0;
        __syncthreads();
        tot[t] += v;
        __syncthreads();
    }
    int pre = (t == 0) ? 0 : tot[t - 1];
#pragma unroll
    for (int c = 0; c < 9; c++) {
        int idx = base + c;
        if (idx < NTOT) off[idx] = pre + loc[c];
    }
    if (t == 1023) off[NTOT] = tot[1023];   // = ETOT
}

__global__ void csr_fill(const int* __restrict__ de, const int* __restrict__ pe,
                         const int* __restrict__ off, int* __restrict__ fill,
                         int* __restrict__ eidx) {
    int e = blockIdx.x * 256 + threadIdx.x;
    if (e >= ETOT) return;
    int s, d;
    if (e < EDRUG) { s = de[e]; d = de[EDRUG + e]; }
    else { int ep = e - EDRUG; s = pe[ep] + NDRUG; d = pe[EPROT + ep] + NDRUG; }
    int pos = off[d] + atomicAdd(&fill[d], 1);
    eidx[pos] = s;
}

// ---------------- GAT: h = x@W (K=N=128) + per-node as/ad ----------------------
__global__ void gat_h(const float* __restrict__ X, const float* __restrict__ W,
                      const float* __restrict__ avs, const float* __restrict__ avd,
                      float* __restrict__ H, float* __restrict__ asn, float* __restrict__ adn) {
    __shared__ float al[16 * 128];
    __shared__ float hl[16][129];
    const int r0 = blockIdx.x * 16;
    const int j  = threadIdx.x;   // 128 threads
    for (int idx = j; idx < 16 * 128; idx += 128) al[idx] = X[r0 * 128 + idx];
    __syncthreads();
    float acc[16];
#pragma unroll
    for (int r = 0; r < 16; r++) acc[r] = 0.f;
    for (int k = 0; k < 128; k++) {
        float bv = W[k * 128 + j];
#pragma unroll
        for (int r = 0; r < 16; r++) acc[r] += al[r * 128 + k] * bv;
    }
#pragma unroll
    for (int r = 0; r < 16; r++) {
        H[(r0 + r) * 128 + j] = acc[r];
        hl[r][j] = acc[r];
    }
    __syncthreads();
    int r = j >> 3, l8 = j & 7;
    float ps = 0.f, pd = 0.f;
    for (int jj = l8; jj < 128; jj += 8) {
        float v = hl[r][jj];
        ps += v * avs[jj];
        pd += v * avd[jj];
    }
    ps += __shfl_down(ps, 4); ps += __shfl_down(ps, 2); ps += __shfl_down(ps, 1);
    pd += __shfl_down(pd, 4); pd += __shfl_down(pd, 2); pd += __shfl_down(pd, 1);
    if (l8 == 0) { asn[r0 + r] = ps; adn[r0 + r] = pd; }
}

// ---------------- GAT gather: softmax-agg + self loop + bias + relu + xsum ------
// One node per 128 threads; edge list wave-uniform; H reads coalesced. No atomics.
__global__ void gat_gather(const int* __restrict__ off, const int* __restrict__ eidx,
                           const float* __restrict__ asn, const float* __restrict__ adn,
                           const float* __restrict__ H, const float* __restrict__ bd,
                           const float* __restrict__ bp, float* __restrict__ Xo,
                           float* __restrict__ xsum, int first) {
    int gid = blockIdx.x * 256 + threadIdx.x;   // NTOT*128 exactly
    int i = gid >> 7, f = gid & 127;
    float adi = adn[i];
    float ev = asn[i] + adi;
    ev = (ev > 0.f) ? ev : 0.2f * ev;
    float w = __expf(ev);                        // self loop
    float acc = w * H[i * 128 + f];
    float den = w;
    int e0 = off[i], e1 = off[i + 1];
    for (int e = e0; e < e1; e++) {
        int s = eidx[e];
        float es = asn[s] + adi;
        es = (es > 0.f) ? es : 0.2f * es;
        float we = __expf(es);
        acc += we * H[s * 128 + f];
        den += we;
    }
    float bias = (i < NDRUG) ? bd[f] : bp[f];
    float val = fmaxf(acc / den + bias, 0.f);
    Xo[gid] = val;
    xsum[gid] = first ? val : (xsum[gid] + val);
}

// ---------------- per-node feature sum of xsum ---------------------------------
__global__ void rowsum(const float* __restrict__ xs, float* __restrict__ sl) {
    int n = blockIdx.x, t = threadIdx.x;  // 64 threads
    float v = xs[n * 128 + t] + xs[n * 128 + t + 64];
    for (int off = 32; off > 0; off >>= 1) v += __shfl_down(v, off);
    if (t == 0) sl[n] = v;
}

// ---------------- WR1[i,k] = sum_j se1w[(i*192+j)*2000+k] (stream 121MB) --------
__global__ void wr1k(const float* __restrict__ W, float* __restrict__ WR1) {
    int k = blockIdx.y * 256 + threadIdx.x;
    int i = blockIdx.x;                       // 0..78
    if (k >= SEHID) return;
    const float* p = W + (size_t)(i * 192) * SEHID + k;
    float a0 = 0.f, a1 = 0.f, a2 = 0.f, a3 = 0.f;
    for (int j = 0; j < 192; j += 4) {
        a0 += p[0];
        a1 += p[(size_t)SEHID];
        a2 += p[2 * (size_t)SEHID];
        a3 += p[3 * (size_t)SEHID];
        p += 4 * (size_t)SEHID;
    }
    WR1[i * SEHID + k] = (a0 + a1) + (a2 + a3);
}

// ---------------- WC1[j,k] = sum_i se1w[(i*192+j)*2000+k] (L3-warm 2nd pass) ----
__global__ void wc1k(const float* __restrict__ W, float* __restrict__ WC1) {
    int k = blockIdx.y * 256 + threadIdx.x;
    int j = blockIdx.x;                       // 0..191
    if (k >= SEHID) return;
    const float* p = W + (size_t)j * SEHID + k;
    const size_t st = (size_t)192 * SEHID;
    float a0 = 0.f, a1 = 0.f, a2 = 0.f, a3 = 0.f;
    int i = 0;
    for (; i < 76; i += 4) {
        a0 += p[0]; a1 += p[st]; a2 += p[2 * st]; a3 += p[3 * st];
        p += 4 * st;
    }
    a0 += p[0]; a1 += p[st]; a2 += p[2 * st];   // 76,77,78
    WC1[j * SEHID + k] = (a0 + a1) + (a2 + a3);
}

// ---------------- cmid = relu((slr@WR1 + slp@WC1)/256 + b); also transposed -----
__global__ void se1_small(const float* __restrict__ sl, const float* __restrict__ WR1,
                          const float* __restrict__ WC1, const float* __restrict__ bias,
                          float* __restrict__ cmid, float* __restrict__ cmidT) {
    int k = blockIdx.x * 256 + threadIdx.x;   // grid.x = 8
    int b = blockIdx.y;                       // 32
    if (k >= SEHID) return;
    float acc = 0.f;
    for (int i = 0; i < 79; i++)  acc += sl[b * 79 + i] * WR1[i * SEHID + k];
    for (int j = 0; j < 192; j++) acc += sl[NDRUG + b * 192 + j] * WC1[j * SEHID + k];
    float v = fmaxf(acc * (1.f / 256.f) + bias[k], 0.f);
    cmid[b * SEHID + k] = v;
    cmidT[k * 32 + b]   = v;
}

// ---------------- sgate[b,ij] = se2b[ij]  (accumulation target for se2) ---------
__global__ void sgate_init(const float* __restrict__ bias, float* __restrict__ sgate) {
    int gid = blockIdx.x * 256 + threadIdx.x;   // 32*15168 exactly, grid 1896
    sgate[gid] = bias[gid % SEIN];
}

// ---------------- SE2: (32 x 2000) @ (2000 x 15168), atomic split-K -------------
// grid (60, 16); block 256; ONE ij per thread -> 32 scalar accs fit VGPRs.
// cmidT slice (125x32 = 16KB) in LDS; kk unrolled x5 with loads batched first.
// 960 blocks -> ~15 waves/CU.
__global__ __launch_bounds__(256) void se2_partial(const float* __restrict__ cmidT,
                                                   const float* __restrict__ W,
                                                   float* __restrict__ sgate) {
    __shared__ float cs[125 * 32];            // 16 KB
    const int ij = blockIdx.x * 256 + threadIdx.x;
    const int ks = blockIdx.y * 125;
    const float4* csrc = (const float4*)(cmidT + ks * 32);   // 16B-aligned
    for (int idx = threadIdx.x; idx < 1000; idx += 256)
        ((float4*)cs)[idx] = csrc[idx];
    __syncthreads();
    const bool in = ij < SEIN;
    float acc[32];
#pragma unroll
    for (int b = 0; b < 32; b++) acc[b] = 0.f;
    const float* wp = W + (size_t)ks * SEIN + ij;
    for (int kk = 0; kk < 125; kk += 5) {
        float w[5];
#pragma unroll
        for (int t = 0; t < 5; t++)
            w[t] = in ? wp[(size_t)t * SEIN] : 0.f;
        wp += 5 * (size_t)SEIN;
#pragma unroll
        for (int t = 0; t < 5; t++) {
            const float* cp = cs + (kk + t) * 32;
#pragma unroll
            for (int b4 = 0; b4 < 32; b4 += 4) {
                float4 a = *(const float4*)(cp + b4);   // uniform addr -> LDS broadcast
                acc[b4 + 0] += a.x * w[t];
                acc[b4 + 1] += a.y * w[t];
                acc[b4 + 2] += a.z * w[t];
                acc[b4 + 3] += a.w * w[t];
            }
        }
    }
    if (in) {
        float* pp = sgate + ij;
#pragma unroll
        for (int b = 0; b < 32; b++) { atomicAdd(pp, acc[b]); pp += SEIN; }
    }
}

// ---------------- wgt = sigmoid(sgate) / inter ----------------------------------
__global__ void se2_fin(const float* __restrict__ sgate, const float* __restrict__ inter,
                        float* __restrict__ wgt) {
    int gid = blockIdx.x * 256 + threadIdx.x;   // 32*15168 exactly, grid 1896
    float s = sgate[gid];
    float sig = 1.f / (1.f + __expf(-s));
    wgt[gid] = sig / inter[gid];
}

// ---------------- row/col sums of wgt over the (79,192) grid (barrier-free) -----
__global__ void wsum(const float* __restrict__ wgt, float* __restrict__ wr,
                     float* __restrict__ wc) {
    int b = blockIdx.x, t = threadIdx.x;   // 256 threads
    if (t < 192) {                          // column sums: coalesced strided reads
        float s = 0.f;
        for (int i = 0; i < 79; i++) s += wgt[b * SEIN + i * 192 + t];
        wc[b * 192 + t] = s;
    }
    int wv = t >> 6, ln = t & 63;           // row sums: one wave per row
    for (int i = wv; i < 79; i += 4) {
        float v = 0.f;
        for (int j = ln; j < 192; j += 64) v += wgt[b * SEIN + i * 192 + j];
        v += __shfl_down(v, 32); v += __shfl_down(v, 16); v += __shfl_down(v, 8);
        v += __shfl_down(v, 4);  v += __shfl_down(v, 2);  v += __shfl_down(v, 1);
        if (ln == 0) wr[b * 79 + i] = v;
    }
}

// ---------------- xx[b,0:128] = x_l^T wr /15168 ; xx[b,128:256] = x_p^T wc ------
__global__ void xxk(const float* __restrict__ xs, const float* __restrict__ wr,
                    const float* __restrict__ wc, float* __restrict__ xx) {
    int b = blockIdx.x, t = threadIdx.x;   // 256 threads
    float acc = 0.f;
    if (t < 128) {
        for (int i = 0; i < 79; i++) acc += xs[(b * 79 + i) * 128 + t] * wr[b * 79 + i];
    } else {
        int f = t - 128;
        for (int j = 0; j < 192; j++) acc += xs[(NDRUG + b * 192 + j) * 128 + f] * wc[b * 192 + j];
    }
    xx[b * 256 + t] = acc * (1.f / 15168.f);
}

// ---------------- head GEMM: one thread per (b,col); acc=1 -> deep ILP ----------
__global__ void mlp_gemm(const float* __restrict__ A, const float* __restrict__ W,
                         const float* __restrict__ bias, float* __restrict__ Raw,
                         float* __restrict__ C, int K, int N, int relu) {
    const int bb = threadIdx.x >> 5, cl = threadIdx.x & 31;
    const int b = blockIdx.y * 8 + bb;
    const int col = blockIdx.x * 32 + cl;
    __shared__ float As[8][64];
    float acc = 0.f;
    for (int k0 = 0; k0 < K; k0 += 64) {
        __syncthreads();
        int idx = threadIdx.x;
        As[idx >> 6][idx & 63] = A[(blockIdx.y * 8 + (idx >> 6)) * K + k0 + (idx & 63)];
        idx += 256;
        As[idx >> 6][idx & 63] = A[(blockIdx.y * 8 + (idx >> 6)) * K + k0 + (idx & 63)];
        __syncthreads();
#pragma unroll 8
        for (int kk = 0; kk < 64; kk++)
            acc += As[bb][kk] * W[(k0 + kk) * N + col];
    }
    float v = acc + bias[col];
    if (Raw) Raw[b * N + col] = v;
    C[b * N + col] = relu ? fmaxf(v, 0.f) : v;
}

// ---------------- final 64->1 projection ---------------------------------------
__global__ void outk(const float* __restrict__ r4, const float* __restrict__ OW,
                     const float* __restrict__ OB, float* __restrict__ outp) {
    int t = threadIdx.x;            // 256 threads = 32 b x 8 lanes
    int b = t >> 3, l = t & 7;
    float v = 0.f;
    for (int j = l; j < 64; j += 8) v += r4[b * 64 + j] * OW[j];
    v += __shfl_down(v, 4); v += __shfl_down(v, 2); v += __shfl_down(v, 1);
    if (l == 0) outp[b] = v + OB[0];
}

extern "C" void kernel_launch(void* const* d_in, const int* in_sizes, int n_in,
                              void* d_out, int out_size, void* d_ws, size_t ws_size,
                              hipStream_t stream) {
    const float* x1    = (const float*)d_in[0];
    const float* x2    = (const float*)d_in[1];
    const float* inter = (const float*)d_in[2];
    const int*   de    = (const int*)d_in[3];
    const int*   pe    = (const int*)d_in[4];
    const float* w1    = (const float*)d_in[5];
    const float* b1    = (const float*)d_in[6];
    const float* w2    = (const float*)d_in[7];
    const float* b2    = (const float*)d_in[8];
    const float* gw    = (const float*)d_in[9];
    const float* gas   = (const float*)d_in[10];
    const float* gad   = (const float*)d_in[11];
    const float* gb    = (const float*)d_in[12];
    const float* se1w  = (const float*)d_in[13];
    const float* se1b  = (const float*)d_in[14];
    const float* se2w  = (const float*)d_in[15];
    const float* se2b  = (const float*)d_in[16];
    const float* fc1w  = (const float*)d_in[17];
    const float* fc1b  = (const float*)d_in[18];
    const float* fc2w  = (const float*)d_in[19];
    const float* fc2b  = (const float*)d_in[20];
    const float* fc3w  = (const float*)d_in[21];
    const float* fc3b  = (const float*)d_in[22];
    const float* fc4w  = (const float*)d_in[23];
    const float* fc4b  = (const float*)d_in[24];
    const float* outw  = (const float*)d_in[25];
    const float* outb  = (const float*)d_in[26];
    float* out = (float*)d_out;
    float* ws  = (float*)d_ws;

    const size_t NF = (size_t)NTOT * 128;   // 1,110,016
    // GAT region (xsum deliberately LAST so sgate can alias xA..hbuf)
    float* xA    = ws;
    float* xB    = ws + NF;
    float* hbuf  = ws + 2 * NF;
    float* xsum  = ws + 3 * NF;
    float* sgate = ws;                      // alias: 32*15168 = 485K << NF
    float* sm    = ws + 4 * NF;
    float* asn   = sm;                     sm += NTOT;
    float* adn   = sm;                     sm += NTOT;
    float* sl    = sm;                     sm += NTOT;
    float* WR1   = sm;                     sm += 79 * SEHID;    // 158000
    float* WC1   = sm;                     sm += 192 * SEHID;   // 384000
    float* cmid  = sm;                     sm += 32 * SEHID;
    float* cmidT = sm;                     sm += 32 * SEHID;
    float* wgt   = sm;                     sm += 32 * SEIN;     // 485376
    float* wr    = sm;                     sm += 32 * 79;
    float* wc    = sm;                     sm += 32 * 192;
    float* xx    = sm;                     sm += 32 * 256;
    float* r1    = sm;                     sm += 32 * 512;
    float* r2    = sm;                     sm += 32 * 256;
    float* r3    = sm;                     sm += 32 * 128;
    float* r4    = sm;                     sm += 32 * 64;
    int*   im    = (int*)sm;
    int*   deg   = im;                     im += NTOT;
    int*   fill  = im;                     im += NTOT;
    int*   off   = im;                     im += NTOT + 1;
    int*   eidx  = im;                     im += ETOT;

    // CSR build (same edges for all 3 GAT layers)
    csr_zero<<<34, 256, 0, stream>>>(deg, fill);
    csr_cnt<<<70, 256, 0, stream>>>(de, pe, deg);
    csr_scan<<<1, 1024, 0, stream>>>(deg, off);
    csr_fill<<<70, 256, 0, stream>>>(de, pe, off, fill, eidx);

    // SE1 weight reductions (independent of GAT results — issue early;
    // wc1k immediately after wr1k so the 121MB se1w is L3-resident)
    wr1k<<<dim3(79, 8), 256, 0, stream>>>(se1w, WR1);
    wc1k<<<dim3(192, 8), 256, 0, stream>>>(se1w, WC1);

    // shared node-embedding MLP (x1 and x2 through w1/w2); stage 1 in xB
    gemm_rt<<<158, 128, 0, stream>>>(x1, w1, b1, xB, 52);
    gemm_rt<<<384, 128, 0, stream>>>(x2, w1, b1, xB + (size_t)NDRUG * 128, 52);
    gemm_rt<<<158, 128, 0, stream>>>(xB, w2, b2, xA, 128);
    gemm_rt<<<384, 128, 0, stream>>>(xB + (size_t)NDRUG * 128, w2, b2, xA + (size_t)NDRUG * 128, 128);

    float* xin = xA;
    float* xout = xB;
    for (int l = 0; l < 3; l++) {
        gat_h<<<158, 128, 0, stream>>>(xin, gw + l * 16384, gas + l * 128, gad + l * 128,
                                       hbuf, asn, adn);
        gat_h<<<384, 128, 0, stream>>>(xin + (size_t)NDRUG * 128, gw + (l + 3) * 16384,
                                       gas + (l + 3) * 128, gad + (l + 3) * 128,
                                       hbuf + (size_t)NDRUG * 128, asn + NDRUG, adn + NDRUG);
        gat_gather<<<4336, 256, 0, stream>>>(off, eidx, asn, adn, hbuf,
                                             gb + l * 128, gb + (l + 3) * 128,
                                             xout, xsum, l == 0 ? 1 : 0);
        float* tmp = xin; xin = xout; xout = tmp;
    }

    rowsum<<<NTOT, 64, 0, stream>>>(xsum, sl);
    se1_small<<<dim3(8, 32), 256, 0, stream>>>(sl, WR1, WC1, se1b, cmid, cmidT);
    sgate_init<<<1896, 256, 0, stream>>>(se2b, sgate);
    se2_partial<<<dim3(60, 16), 256, 0, stream>>>(cmidT, se2w, sgate);
    se2_fin<<<1896, 256, 0, stream>>>(sgate, inter, wgt);
    wsum<<<32, 256, 0, stream>>>(wgt, wr, wc);
    xxk<<<32, 256, 0, stream>>>(xsum, wr, wc, xx);

    mlp_gemm<<<dim3(16, 4), 256, 0, stream>>>(xx, fc1w, fc1b, out + 32, r1, 256, 512, 1);
    mlp_gemm<<<dim3(8, 4), 256, 0, stream>>>(r1, fc2w, fc2b, nullptr, r2, 512, 256, 1);
    mlp_gemm<<<dim3(4, 4), 256, 0, stream>>>(r2, fc3w, fc3b, nullptr, r3, 256, 128, 1);
    mlp_gemm<<<dim3(2, 4), 256, 0, stream>>>(r3, fc4w, fc4b, nullptr, r4, 128, 64, 1);
    outk<<<1, 256, 0, stream>>>(r4, outw, outb, out);
}